// Round 18
// baseline (306.070 us; speedup 1.0000x reference)
//
#include <hip/hip_runtime.h>
#include <math.h>

// ---------------------------------------------------------------------------
// RefEncoder, MFMA edition (round 18: conv2/conv3 NWAVE 8->4, grids doubled).
// gelu via v_exp_f32 sigmoid form.
// conv1: fp32 direct, block 256 = tx16 x ty8 x cz2; tile 8 oy x 128 ox x 16 co;
//   window 17x260 LDS (float4-staged per ci), weights LDS broadcast.
// conv2/3/4: implicit-GEMM via v_mfma_f32_16x16x32_f16, fp16 2-term split:
//   x = hi + lo/4096;  C = A_hi*B_hi ; Ccross = A_hi*B_lo' + A_lo'*B_hi
//   result = C + Ccross/4096 (dropped al*bl ~2^-24 rel: fp32-class)
// B fragments per-wave from global (fragment-ordered, L2-resident), no B-LDS.
// conv2: NWAVE=4, grid 2048; conv3: NWAVE=4, grid 1024 (4-wave blocks pack
//   finer into the 3 LDS slots/CU; conv4 precedent).
// conv4: NWAVE=4 + KSPLIT=4 -> grid 1024, fp32 partials; reduce4_k + bias.
// head: scores[px,m,k] = sum_d latent[px,m*64+d] * M[m,k,d] (M precomputed);
//   block = 4px x 4m x 16kq, 16 codes/thread, grid 1024.
// Output (int32): 16384 codes [n,hh,ww,m] + tail [256,256]
// ---------------------------------------------------------------------------

typedef _Float16 half8 __attribute__((ext_vector_type(8)));
typedef float floatx4 __attribute__((ext_vector_type(4)));
typedef unsigned int u32;
typedef unsigned short u16;

__device__ __forceinline__ float gelu_tanh(float x) {
    // x * sigmoid(1.5957691216*x + 0.07135481627*x^3)  (== tanh-form gelu)
    float x3 = x * x * x;
    float t = 1.5957691216057308f * x + 0.07135481627333636f * x3;
    return x / (1.0f + __expf(-t));
}

__device__ __forceinline__ u32 pack_split(float v) {
    _Float16 h = (_Float16)v;
    _Float16 l = (_Float16)((v - (float)h) * 4096.0f);
    union { _Float16 f; u16 s; } a, b;
    a.f = h; b.f = l;
    return (u32)a.s | ((u32)b.s << 16);
}

// ---- weight prep: OIHW fp32 -> B-fragment-ordered fp16 hi/lo planes -------
template <int Ci, int Co>
__global__ void prep_w(const float* __restrict__ W, _Float16* __restrict__ dH,
                       _Float16* __restrict__ dL) {
    constexpr int KC = Ci / 32, NTg = Co / 16;
    int lin = blockIdx.x * 256 + threadIdx.x;
    if (lin >= 9 * KC * NTg * 64) return;
    int l = lin & 63;
    int q = lin >> 6;
    int nt = q % NTg; q /= NTg;
    int kc = q % KC;
    int tap = q / KC;
    int co = nt * 16 + (l & 15);
    int ci0 = kc * 32 + ((l >> 4) << 3);
#pragma unroll
    for (int j = 0; j < 8; ++j) {
        float v = W[((size_t)co * Ci + ci0 + j) * 9 + tap];
        _Float16 h = (_Float16)v;
        _Float16 lo = (_Float16)((v - (float)h) * 4096.0f);
        dH[(size_t)lin * 8 + j] = h;
        dL[(size_t)lin * 8 + j] = lo;
    }
}

// ---- conv1: 3->64, fp32 direct (round-12 tile), float4 staging -----------
__launch_bounds__(256)
__global__ void conv1_k(const float* __restrict__ x, const float* __restrict__ w,
                        const float* __restrict__ bias, u32* __restrict__ out) {
    __shared__ float win[17 * 260];     // one ci slice, rows iy0..iy0+16
    __shared__ float wsh[27 * 64];      // [ci*9+tap][co]
    const int t = threadIdx.x;
    const int tx = t & 15, ty = (t >> 4) & 7, cz = t >> 7;
    int bx = blockIdx.x;
    const int cg = bx & 3;
    const int oyt = (bx >> 2) & 15;
    const int n = bx >> 6;
    const int co0 = cg * 16 + cz * 8;
    const int oy = oyt * 8 + ty;
    const int ox0 = tx * 8;
    const int iy0 = oyt * 16;

    for (int e = t; e < 27 * 64; e += 256) {
        int co = e & 63, ct = e >> 6;   // ct = ci*9+ky*3+kx
        wsh[ct * 64 + co] = w[co * 27 + ct];
    }

    float acc[8][8];
#pragma unroll
    for (int c = 0; c < 8; ++c)
#pragma unroll
        for (int p = 0; p < 8; ++p) acc[c][p] = 0.0f;

    for (int ci = 0; ci < 3; ++ci) {
        __syncthreads();
        // float4 staging: 17 rows x 65 quads (quad 64 = cols 256..259 = pad)
        for (int e = t; e < 17 * 65; e += 256) {
            int r = e / 65, c4 = (e - r * 65) * 4;
            int iy = iy0 + r;
            float4 v = {0.0f, 0.0f, 0.0f, 0.0f};
            if (c4 < 256 && iy < 256) {
                float4 g = *(const float4*)&x[((size_t)(n * 3 + ci) * 256 + iy) * 256 + c4];
                v.x = 2.0f * g.x - 1.0f; v.y = 2.0f * g.y - 1.0f;
                v.z = 2.0f * g.z - 1.0f; v.w = 2.0f * g.w - 1.0f;
            }
            *(float4*)&win[r * 260 + c4] = v;
        }
        __syncthreads();

#pragma unroll
        for (int ky = 0; ky < 3; ++ky) {
            const float* rowp = &win[(2 * ty + ky) * 260 + 16 * tx];
            float rv[20];
#pragma unroll
            for (int q = 0; q < 5; ++q) {
                float4 v4 = *(const float4*)(rowp + 4 * q);
                rv[4 * q + 0] = v4.x; rv[4 * q + 1] = v4.y;
                rv[4 * q + 2] = v4.z; rv[4 * q + 3] = v4.w;
            }
#pragma unroll
            for (int kx = 0; kx < 3; ++kx) {
                const float* wp = &wsh[(ci * 9 + ky * 3 + kx) * 64 + co0];
                float wv[8];
#pragma unroll
                for (int q = 0; q < 2; ++q) {
                    float4 v4 = *(const float4*)(wp + 4 * q);  // broadcast
                    wv[4 * q + 0] = v4.x; wv[4 * q + 1] = v4.y;
                    wv[4 * q + 2] = v4.z; wv[4 * q + 3] = v4.w;
                }
#pragma unroll
                for (int c = 0; c < 8; ++c)
#pragma unroll
                    for (int p = 0; p < 8; ++p)
                        acc[c][p] += rv[2 * p + kx] * wv[c];
            }
        }
    }

    float bj[8];
#pragma unroll
    for (int c = 0; c < 8; ++c) bj[c] = bias[co0 + c];
#pragma unroll
    for (int p = 0; p < 8; ++p) {
        int ox = ox0 + p;
        size_t base = ((size_t)(n * 128 + oy) * 128 + ox) * 64 + co0;
        uint4 s0, s1;
        s0.x = pack_split(gelu_tanh(acc[0][p] + bj[0]));
        s0.y = pack_split(gelu_tanh(acc[1][p] + bj[1]));
        s0.z = pack_split(gelu_tanh(acc[2][p] + bj[2]));
        s0.w = pack_split(gelu_tanh(acc[3][p] + bj[3]));
        s1.x = pack_split(gelu_tanh(acc[4][p] + bj[4]));
        s1.y = pack_split(gelu_tanh(acc[5][p] + bj[5]));
        s1.z = pack_split(gelu_tanh(acc[6][p] + bj[6]));
        s1.w = pack_split(gelu_tanh(acc[7][p] + bj[7]));
        *(uint4*)&out[base] = s0;
        *(uint4*)&out[base + 4] = s1;
    }
}

// ---- MFMA conv: stride-2 3x3, NHWC packed-half2 in ----------------------
template <int Ci, int Co, int Hi, int Wi, int NWAVE, int KSPLIT, bool GELU, bool SPLIT>
__launch_bounds__(NWAVE * 64)
__global__ void conv_mfma(const u32* __restrict__ in, const _Float16* __restrict__ WbH,
                          const _Float16* __restrict__ WbL, const float* __restrict__ bias,
                          void* __restrict__ outp) {
    constexpr int Ho = Hi / 2, Wo = Wi / 2;
    constexpr int KC = Ci / 32, NTg = Co / 16;
    constexpr int OYT = Ho / 4, OXT = Wo / 16, CGT = Co / (16 * NWAVE);
    constexpr int WC = 33, CIBP = 40;
    constexpr int NT = NWAVE * 64;
    constexpr int KCS = KC / KSPLIT;
    __shared__ _Float16 AH[9 * WC * CIBP], AL[9 * WC * CIBP];  // 47.5 KB total

    const int t = threadIdx.x, l = t & 63, wid = t >> 6;
    const int wm = wid / (NWAVE / 2), wn = wid % (NWAVE / 2);
    int bx = blockIdx.x;
    const int ks = bx % KSPLIT;  bx /= KSPLIT;
    const int cg = bx % CGT;  bx /= CGT;
    const int oxt = bx % OXT; bx /= OXT;
    const int oyt = bx % OYT; bx /= OYT;
    const int n = bx;
    const int oy0 = oyt * 4, ox0 = oxt * 16, co0 = cg * 16 * NWAVE, nt0 = co0 >> 4;
    const int iy0 = oy0 * 2, ix0 = ox0 * 2;

    floatx4 aM[2][2], aX[2][2];
    floatx4 zz = {0.0f, 0.0f, 0.0f, 0.0f};
#pragma unroll
    for (int a = 0; a < 2; ++a)
#pragma unroll
        for (int b = 0; b < 2; ++b) { aM[a][b] = zz; aX[a][b] = zz; }

    const int bfrag = (wn * 2) * 512 + l * 8;

    for (int kc = ks * KCS; kc < (ks + 1) * KCS; ++kc) {
        __syncthreads();
        for (int e = t; e < 9 * WC * 4; e += NT) {
            int og = e & 3, px = e >> 2;
            int r = px / WC, cx = px - r * WC;
            int iy = iy0 + r, ix = ix0 + cx;
            union { float4 f4[2]; u32 u[8]; } buf;
            if (iy < Hi && ix < Wi) {
                const float4* g = (const float4*)(in + (((size_t)(n * Hi + iy) * Wi + ix) * Ci + kc * 32 + og * 8));
                buf.f4[0] = g[0]; buf.f4[1] = g[1];
            } else {
#pragma unroll
                for (int k2 = 0; k2 < 8; ++k2) buf.u[k2] = 0;
            }
            union { float4 f4; u16 s[8]; } hh, ll;
#pragma unroll
            for (int k2 = 0; k2 < 8; ++k2) {
                hh.s[k2] = (u16)buf.u[k2];
                ll.s[k2] = (u16)(buf.u[k2] >> 16);
            }
            int off = px * CIBP + og * 8;
            *(float4*)&AH[off] = hh.f4;
            *(float4*)&AL[off] = ll.f4;
        }
        __syncthreads();

#pragma unroll
        for (int tap = 0; tap < 9; ++tap) {
            const size_t src = ((size_t)(tap * KC + kc) * NTg + nt0) * 512 + bfrag;
            half8 bh[2], bl[2];
#pragma unroll
            for (int b = 0; b < 2; ++b) {
                bh[b] = *(const half8*)&WbH[src + b * 512];
                bl[b] = *(const half8*)&WbL[src + b * 512];
            }
            const int ky = tap / 3, kx = tap - ky * 3;
#pragma unroll
            for (int a = 0; a < 2; ++a) {
                int mt = wm * 2 + a;
                int off = ((2 * mt + ky) * WC + 2 * (l & 15) + kx) * CIBP + (l >> 4) * 8;
                half8 ah = *(half8*)&AH[off];
                half8 al = *(half8*)&AL[off];
#pragma unroll
                for (int b = 0; b < 2; ++b) {
                    aM[a][b] = __builtin_amdgcn_mfma_f32_16x16x32_f16(ah, bh[b], aM[a][b], 0, 0, 0);
                    aX[a][b] = __builtin_amdgcn_mfma_f32_16x16x32_f16(ah, bl[b], aX[a][b], 0, 0, 0);
                    aX[a][b] = __builtin_amdgcn_mfma_f32_16x16x32_f16(al, bh[b], aX[a][b], 0, 0, 0);
                }
            }
        }
    }

#pragma unroll
    for (int a = 0; a < 2; ++a) {
        int oy = oy0 + wm * 2 + a;
#pragma unroll
        for (int b = 0; b < 2; ++b) {
            int co = co0 + (wn * 2 + b) * 16 + (l & 15);
            float bj = (KSPLIT == 1) ? bias[co] : 0.0f;
#pragma unroll
            for (int r = 0; r < 4; ++r) {
                int ox = ox0 + (l >> 4) * 4 + r;
                float v = aM[a][b][r] + aX[a][b][r] * (1.0f / 4096.0f) + bj;
                size_t oidx = ((size_t)(n * Ho + oy) * Wo + ox) * Co + co;
                if (KSPLIT > 1) {
                    ((float*)outp)[(size_t)ks * (16 * Ho * Wo * Co) + oidx] = v;
                } else {
                    if (GELU) v = gelu_tanh(v);
                    if (SPLIT) ((u32*)outp)[oidx] = pack_split(v);
                    else       ((float*)outp)[oidx] = v;
                }
            }
        }
    }
}

// ---- reduce conv4 partials + bias -> NHWC fp32 latent --------------------
__global__ void reduce4_k(const float* __restrict__ part,
                          const float* __restrict__ bias,
                          float* __restrict__ out) {
    constexpr int PS4 = 16 * 16 * 16 * 256 / 4;   // partial stride in float4
    int gid = blockIdx.x * 256 + threadIdx.x;     // 262144 total
    const float4* p = (const float4*)part;
    float4 s = p[gid];
    float4 q1 = p[PS4 + gid];
    float4 q2 = p[2 * PS4 + gid];
    float4 q3 = p[3 * PS4 + gid];
    s.x += q1.x; s.y += q1.y; s.z += q1.z; s.w += q1.w;
    s.x += q2.x; s.y += q2.y; s.z += q2.z; s.w += q2.w;
    s.x += q3.x; s.y += q3.y; s.z += q3.z; s.w += q3.w;
    float4 b = *(const float4*)&bias[(gid * 4) & 255];
    s.x += b.x; s.y += b.y; s.z += b.z; s.w += b.w;
    ((float4*)out)[gid] = s;
}

// ---- head precompute ------------------------------------------------------
__global__ void kproj_kernel(const float* __restrict__ cb,
                             const float* __restrict__ wk,
                             float* __restrict__ kp) {
    int m = blockIdx.x >> 8;
    int k = blockIdx.x & 255;
    int c = threadIdx.x;
    const float* cbp = cb + (size_t)(m * 256 + k) * 64;
    const float* wkp = wk + (size_t)(m * 64 + c) * 64;
    float acc = 0.0f;
#pragma unroll 8
    for (int d = 0; d < 64; ++d) acc += cbp[d] * wkp[d];
    kp[(size_t)(m * 256 + k) * 64 + c] = acc;
}

__global__ void m_kernel(const float* __restrict__ wq,
                         const float* __restrict__ kp,
                         float* __restrict__ M) {
    int m = blockIdx.x >> 8;
    int k = blockIdx.x & 255;
    int d = threadIdx.x;
    const float* kpp = &kp[(size_t)(m * 256 + k) * 64];
    const float* wqp = &wq[(size_t)m * 64 * 64 + d];
    float acc = 0.0f;
#pragma unroll 8
    for (int c = 0; c < 64; ++c) acc += wqp[c * 64] * kpp[c];
    M[((size_t)(m * 256 + k)) * 64 + d] = acc;
}

// ---- head: scores = lat . M, argmax over k -------------------------------
// block = 4px x 4m x 16kq; thread scans 16 codes; grid 1024 (4 blocks/CU).
__launch_bounds__(256)
__global__ void head_kernel(const float* __restrict__ latent,  // NHWC fp32
                            const float* __restrict__ M,
                            int* __restrict__ out) {
    __shared__ float rs[256];
    __shared__ int rk[256];
    const int t = threadIdx.x;
    const int px = t & 3, m = (t >> 2) & 3, kq = t >> 4;   // kq 0..15
    const int pix = blockIdx.x * 4 + px;

    float4 lr[16];
    const float4* lp = (const float4*)&latent[(size_t)pix * 256 + m * 64];
#pragma unroll
    for (int d = 0; d < 16; ++d) lr[d] = lp[d];

    float best = -INFINITY;
    int bestk = 0;
    const float4* Mp = (const float4*)&M[(size_t)(m * 256 + kq * 16) * 64];
#pragma unroll 4
    for (int kk = 0; kk < 16; ++kk) {
        float s0 = 0.0f, s1 = 0.0f, s2 = 0.0f, s3 = 0.0f;
#pragma unroll
        for (int d = 0; d < 16; ++d) {
            float4 mv = Mp[kk * 16 + d];
            s0 += lr[d].x * mv.x; s1 += lr[d].y * mv.y;
            s2 += lr[d].z * mv.z; s3 += lr[d].w * mv.w;
        }
        float s = (s0 + s1) + (s2 + s3);
        if (s > best) { best = s; bestk = kq * 16 + kk; }  // ascending: keeps lowest
    }
    rs[t] = best; rk[t] = bestk;
    __syncthreads();
    if (kq == 0) {
#pragma unroll
        for (int q = 1; q < 16; ++q) {                     // ascending kq ranges
            float sv = rs[t + 16 * q];
            int kv = rk[t + 16 * q];
            if (sv > best || (sv == best && kv < bestk)) { best = sv; bestk = kv; }
        }
        out[pix * 4 + m] = bestk;
    }
    if (blockIdx.x == 0 && t == 0) { out[16384] = 256; out[16385] = 256; }
}

extern "C" void kernel_launch(void* const* d_in, const int* in_sizes, int n_in,
                              void* d_out, int out_size, void* d_ws, size_t ws_size,
                              hipStream_t stream) {
    const float* x  = (const float*)d_in[0];
    const float* w1 = (const float*)d_in[1];  const float* b1 = (const float*)d_in[2];
    const float* w2 = (const float*)d_in[3];  const float* b2 = (const float*)d_in[4];
    const float* w3 = (const float*)d_in[5];  const float* b3 = (const float*)d_in[6];
    const float* w4 = (const float*)d_in[7];  const float* b4 = (const float*)d_in[8];
    const float* cb = (const float*)d_in[9];
    const float* wq = (const float*)d_in[10];
    const float* wk = (const float*)d_in[11];
    int* out = (int*)d_out;

    char* ws = (char*)d_ws;
    u32*   buf1 = (u32*)ws;                         // 16*128*128*64 u32 = 64 MiB
    u32*   buf2 = (u32*)(ws + 67108864);            // 16*64*64*128  u32 = 32 MiB
    u32*   buf3 = (u32*)(ws + 100663296);           // 16*32*32*256  u32 = 16 MiB
    float* buf4 = (float*)(ws + 117440512);         // 16*16*16*256  f32 =  4 MiB
    float* kp   = (float*)(ws + 121634816);         // 256 KiB
    float* Mbuf = (float*)(ws + 121634816 + 262144);// 256 KiB

    _Float16* w2H = (_Float16*)(ws + 100663296);    // in buf3 (dead until conv3)
    _Float16* w2L = w2H + 9 * 2 * 8 * 512;
    _Float16* w3H = (_Float16*)ws;                  // in buf1 (dead after conv2)
    _Float16* w3L = w3H + 9 * 4 * 16 * 512;
    _Float16* w4H = w3L + 9 * 4 * 16 * 512;
    _Float16* w4L = w4H + 9 * 8 * 16 * 512;
    float* part4 = (float*)(ws + 67108864);         // buf2 region (dead after conv3), 16 MiB

    prep_w<64, 128><<<36, 256, 0, stream>>>(w2, w2H, w2L);
    conv1_k<<<1024, 256, 0, stream>>>(x, w1, b1, buf1);
    conv_mfma<64, 128, 128, 128, 4, 1, true, true><<<2048, 256, 0, stream>>>(buf1, w2H, w2L, b2, buf2);
    prep_w<128, 256><<<144, 256, 0, stream>>>(w3, w3H, w3L);
    prep_w<256, 256><<<288, 256, 0, stream>>>(w4, w4H, w4L);
    conv_mfma<128, 256, 64, 64, 4, 1, true, true><<<1024, 256, 0, stream>>>(buf2, w3H, w3L, b3, buf3);
    kproj_kernel<<<4 * 256, 64, 0, stream>>>(cb, wk, kp);
    m_kernel<<<4 * 256, 64, 0, stream>>>(wq, kp, Mbuf);
    conv_mfma<256, 256, 32, 32, 4, 4, false, false><<<1024, 256, 0, stream>>>(buf3, w4H, w4L, b4, part4);
    reduce4_k<<<1024, 256, 0, stream>>>(part4, b4, buf4);
    head_kernel<<<1024, 256, 0, stream>>>(buf4, Mbuf, out);
}

// Round 19
// 293.329 us; speedup vs baseline: 1.0434x; 1.0434x over previous
//
#include <hip/hip_runtime.h>
#include <math.h>

// ---------------------------------------------------------------------------
// RefEncoder, MFMA edition (round 19: revert conv2/3 to NWAVE=8; add register
// -prefetch pipeline to conv_mfma staging — kc+1 loads issued before tap
// compute so global latency overlaps MFMA instead of stalling the barrier).
// gelu via v_exp_f32 sigmoid form.
// conv1: fp32 direct, float4-staged 17x260 window, weights LDS broadcast.
// conv2/3/4: implicit-GEMM via v_mfma_f32_16x16x32_f16, fp16 2-term split:
//   x = hi + lo/4096;  C = A_hi*B_hi ; Ccross = A_hi*B_lo' + A_lo'*B_hi
//   result = C + Ccross/4096 (dropped al*bl ~2^-24 rel: fp32-class)
// B fragments per-wave from global (fragment-ordered, L2-resident), no B-LDS.
// conv4: NWAVE=4 + KSPLIT=4, fp32 partials; reduce4_k + bias.
// head: block = 4px x 4m x 16kq, 16 codes/thread, grid 1024.
// Output (int32): 16384 codes [n,hh,ww,m] + tail [256,256]
// ---------------------------------------------------------------------------

typedef _Float16 half8 __attribute__((ext_vector_type(8)));
typedef float floatx4 __attribute__((ext_vector_type(4)));
typedef unsigned int u32;
typedef unsigned short u16;

__device__ __forceinline__ float gelu_tanh(float x) {
    // x * sigmoid(1.5957691216*x + 0.07135481627*x^3)  (== tanh-form gelu)
    float x3 = x * x * x;
    float t = 1.5957691216057308f * x + 0.07135481627333636f * x3;
    return x / (1.0f + __expf(-t));
}

__device__ __forceinline__ u32 pack_split(float v) {
    _Float16 h = (_Float16)v;
    _Float16 l = (_Float16)((v - (float)h) * 4096.0f);
    union { _Float16 f; u16 s; } a, b;
    a.f = h; b.f = l;
    return (u32)a.s | ((u32)b.s << 16);
}

// ---- weight prep: OIHW fp32 -> B-fragment-ordered fp16 hi/lo planes -------
template <int Ci, int Co>
__global__ void prep_w(const float* __restrict__ W, _Float16* __restrict__ dH,
                       _Float16* __restrict__ dL) {
    constexpr int KC = Ci / 32, NTg = Co / 16;
    int lin = blockIdx.x * 256 + threadIdx.x;
    if (lin >= 9 * KC * NTg * 64) return;
    int l = lin & 63;
    int q = lin >> 6;
    int nt = q % NTg; q /= NTg;
    int kc = q % KC;
    int tap = q / KC;
    int co = nt * 16 + (l & 15);
    int ci0 = kc * 32 + ((l >> 4) << 3);
#pragma unroll
    for (int j = 0; j < 8; ++j) {
        float v = W[((size_t)co * Ci + ci0 + j) * 9 + tap];
        _Float16 h = (_Float16)v;
        _Float16 lo = (_Float16)((v - (float)h) * 4096.0f);
        dH[(size_t)lin * 8 + j] = h;
        dL[(size_t)lin * 8 + j] = lo;
    }
}

// ---- conv1: 3->64, fp32 direct (round-12 tile), float4 staging -----------
__launch_bounds__(256)
__global__ void conv1_k(const float* __restrict__ x, const float* __restrict__ w,
                        const float* __restrict__ bias, u32* __restrict__ out) {
    __shared__ float win[17 * 260];     // one ci slice, rows iy0..iy0+16
    __shared__ float wsh[27 * 64];      // [ci*9+tap][co]
    const int t = threadIdx.x;
    const int tx = t & 15, ty = (t >> 4) & 7, cz = t >> 7;
    int bx = blockIdx.x;
    const int cg = bx & 3;
    const int oyt = (bx >> 2) & 15;
    const int n = bx >> 6;
    const int co0 = cg * 16 + cz * 8;
    const int oy = oyt * 8 + ty;
    const int ox0 = tx * 8;
    const int iy0 = oyt * 16;

    for (int e = t; e < 27 * 64; e += 256) {
        int co = e & 63, ct = e >> 6;   // ct = ci*9+ky*3+kx
        wsh[ct * 64 + co] = w[co * 27 + ct];
    }

    float acc[8][8];
#pragma unroll
    for (int c = 0; c < 8; ++c)
#pragma unroll
        for (int p = 0; p < 8; ++p) acc[c][p] = 0.0f;

    for (int ci = 0; ci < 3; ++ci) {
        __syncthreads();
        // float4 staging: 17 rows x 65 quads (quad 64 = cols 256..259 = pad)
        for (int e = t; e < 17 * 65; e += 256) {
            int r = e / 65, c4 = (e - r * 65) * 4;
            int iy = iy0 + r;
            float4 v = {0.0f, 0.0f, 0.0f, 0.0f};
            if (c4 < 256 && iy < 256) {
                float4 g = *(const float4*)&x[((size_t)(n * 3 + ci) * 256 + iy) * 256 + c4];
                v.x = 2.0f * g.x - 1.0f; v.y = 2.0f * g.y - 1.0f;
                v.z = 2.0f * g.z - 1.0f; v.w = 2.0f * g.w - 1.0f;
            }
            *(float4*)&win[r * 260 + c4] = v;
        }
        __syncthreads();

#pragma unroll
        for (int ky = 0; ky < 3; ++ky) {
            const float* rowp = &win[(2 * ty + ky) * 260 + 16 * tx];
            float rv[20];
#pragma unroll
            for (int q = 0; q < 5; ++q) {
                float4 v4 = *(const float4*)(rowp + 4 * q);
                rv[4 * q + 0] = v4.x; rv[4 * q + 1] = v4.y;
                rv[4 * q + 2] = v4.z; rv[4 * q + 3] = v4.w;
            }
#pragma unroll
            for (int kx = 0; kx < 3; ++kx) {
                const float* wp = &wsh[(ci * 9 + ky * 3 + kx) * 64 + co0];
                float wv[8];
#pragma unroll
                for (int q = 0; q < 2; ++q) {
                    float4 v4 = *(const float4*)(wp + 4 * q);  // broadcast
                    wv[4 * q + 0] = v4.x; wv[4 * q + 1] = v4.y;
                    wv[4 * q + 2] = v4.z; wv[4 * q + 3] = v4.w;
                }
#pragma unroll
                for (int c = 0; c < 8; ++c)
#pragma unroll
                    for (int p = 0; p < 8; ++p)
                        acc[c][p] += rv[2 * p + kx] * wv[c];
            }
        }
    }

    float bj[8];
#pragma unroll
    for (int c = 0; c < 8; ++c) bj[c] = bias[co0 + c];
#pragma unroll
    for (int p = 0; p < 8; ++p) {
        int ox = ox0 + p;
        size_t base = ((size_t)(n * 128 + oy) * 128 + ox) * 64 + co0;
        uint4 s0, s1;
        s0.x = pack_split(gelu_tanh(acc[0][p] + bj[0]));
        s0.y = pack_split(gelu_tanh(acc[1][p] + bj[1]));
        s0.z = pack_split(gelu_tanh(acc[2][p] + bj[2]));
        s0.w = pack_split(gelu_tanh(acc[3][p] + bj[3]));
        s1.x = pack_split(gelu_tanh(acc[4][p] + bj[4]));
        s1.y = pack_split(gelu_tanh(acc[5][p] + bj[5]));
        s1.z = pack_split(gelu_tanh(acc[6][p] + bj[6]));
        s1.w = pack_split(gelu_tanh(acc[7][p] + bj[7]));
        *(uint4*)&out[base] = s0;
        *(uint4*)&out[base + 4] = s1;
    }
}

// ---- MFMA conv: stride-2 3x3, NHWC packed-half2 in ----------------------
// Register-prefetch pipeline: stage[kc+1] loads are issued before the tap
// compute of kc, so global latency overlaps MFMA (no barrier drain on loads).
template <int Ci, int Co, int Hi, int Wi, int NWAVE, int KSPLIT, bool GELU, bool SPLIT>
__launch_bounds__(NWAVE * 64)
__global__ void conv_mfma(const u32* __restrict__ in, const _Float16* __restrict__ WbH,
                          const _Float16* __restrict__ WbL, const float* __restrict__ bias,
                          void* __restrict__ outp) {
    constexpr int Ho = Hi / 2, Wo = Wi / 2;
    constexpr int KC = Ci / 32, NTg = Co / 16;
    constexpr int OYT = Ho / 4, OXT = Wo / 16, CGT = Co / (16 * NWAVE);
    constexpr int WC = 33, CIBP = 40;
    constexpr int NT = NWAVE * 64;
    constexpr int KCS = KC / KSPLIT;
    constexpr int NELEM = 9 * WC * 4;          // 1188 units of 8 u32
    constexpr int NFULL = NELEM / NT;          // fully-populated prefetch iters
    constexpr int NREM = NELEM - NFULL * NT;   // remainder (direct-load) lanes
    __shared__ _Float16 AH[9 * WC * CIBP], AL[9 * WC * CIBP];  // 47.5 KB total

    const int t = threadIdx.x, l = t & 63, wid = t >> 6;
    const int wm = wid / (NWAVE / 2), wn = wid % (NWAVE / 2);
    int bx = blockIdx.x;
    const int ks = bx % KSPLIT;  bx /= KSPLIT;
    const int cg = bx % CGT;  bx /= CGT;
    const int oxt = bx % OXT; bx /= OXT;
    const int oyt = bx % OYT; bx /= OYT;
    const int n = bx;
    const int oy0 = oyt * 4, ox0 = oxt * 16, co0 = cg * 16 * NWAVE, nt0 = co0 >> 4;
    const int iy0 = oy0 * 2, ix0 = ox0 * 2;

    floatx4 aM[2][2], aX[2][2];
    floatx4 zz = {0.0f, 0.0f, 0.0f, 0.0f};
#pragma unroll
    for (int a = 0; a < 2; ++a)
#pragma unroll
        for (int b = 0; b < 2; ++b) { aM[a][b] = zz; aX[a][b] = zz; }

    const int bfrag = (wn * 2) * 512 + l * 8;

    // staging descriptors (kc-invariant; goff<0 marks out-of-window -> zeros)
    int goff[NFULL + 1], loff[NFULL + 1];
#pragma unroll
    for (int i = 0; i <= NFULL; ++i) {
        int e = t + NT * i;
        int og = e & 3, px = e >> 2;
        int r = px / WC, cx = px - r * WC;
        int iy = iy0 + r, ix = ix0 + cx;
        bool ok = (e < NELEM) && (iy < Hi) && (ix < Wi);
        goff[i] = ok ? (((n * Hi + iy) * Wi + ix) * Ci + og * 8) : -1;
        loff[i] = (e < NELEM) ? (px * CIBP + og * 8) : 0;
    }

    const int kc0 = ks * KCS, kcEnd = kc0 + KCS;
    uint4 stage[NFULL][2];
#pragma unroll
    for (int i = 0; i < NFULL; ++i) {
        stage[i][0] = uint4{0, 0, 0, 0};
        stage[i][1] = uint4{0, 0, 0, 0};
        if (goff[i] >= 0) {
            const uint4* g = (const uint4*)(in + (size_t)goff[i] + kc0 * 32);
            stage[i][0] = g[0]; stage[i][1] = g[1];
        }
    }

    for (int kc = kc0; kc < kcEnd; ++kc) {
        __syncthreads();
#pragma unroll
        for (int i = 0; i < NFULL; ++i) {
            u32 uu[8];
            *(uint4*)&uu[0] = stage[i][0];
            *(uint4*)&uu[4] = stage[i][1];
            union { float4 f4; u16 s[8]; } hh, ll;
#pragma unroll
            for (int k2 = 0; k2 < 8; ++k2) {
                hh.s[k2] = (u16)uu[k2];
                ll.s[k2] = (u16)(uu[k2] >> 16);
            }
            *(float4*)&AH[loff[i]] = hh.f4;
            *(float4*)&AL[loff[i]] = ll.f4;
        }
        if (NREM && t < NREM) {       // remainder unit: direct load + store
            u32 uu[8] = {0, 0, 0, 0, 0, 0, 0, 0};
            if (goff[NFULL] >= 0) {
                const uint4* g = (const uint4*)(in + (size_t)goff[NFULL] + kc * 32);
                *(uint4*)&uu[0] = g[0]; *(uint4*)&uu[4] = g[1];
            }
            union { float4 f4; u16 s[8]; } hh, ll;
#pragma unroll
            for (int k2 = 0; k2 < 8; ++k2) {
                hh.s[k2] = (u16)uu[k2];
                ll.s[k2] = (u16)(uu[k2] >> 16);
            }
            *(float4*)&AH[loff[NFULL]] = hh.f4;
            *(float4*)&AL[loff[NFULL]] = ll.f4;
        }
        __syncthreads();

        // issue next kc's staging loads now; they stay in flight during taps
        if (kc + 1 < kcEnd) {
#pragma unroll
            for (int i = 0; i < NFULL; ++i) {
                if (goff[i] >= 0) {
                    const uint4* g = (const uint4*)(in + (size_t)goff[i] + (kc + 1) * 32);
                    stage[i][0] = g[0]; stage[i][1] = g[1];
                }
            }
        }

#pragma unroll
        for (int tap = 0; tap < 9; ++tap) {
            const size_t src = ((size_t)(tap * KC + kc) * NTg + nt0) * 512 + bfrag;
            half8 bh[2], bl[2];
#pragma unroll
            for (int b = 0; b < 2; ++b) {
                bh[b] = *(const half8*)&WbH[src + b * 512];
                bl[b] = *(const half8*)&WbL[src + b * 512];
            }
            const int ky = tap / 3, kx = tap - ky * 3;
#pragma unroll
            for (int a = 0; a < 2; ++a) {
                int mt = wm * 2 + a;
                int off = ((2 * mt + ky) * WC + 2 * (l & 15) + kx) * CIBP + (l >> 4) * 8;
                half8 ah = *(half8*)&AH[off];
                half8 al = *(half8*)&AL[off];
#pragma unroll
                for (int b = 0; b < 2; ++b) {
                    aM[a][b] = __builtin_amdgcn_mfma_f32_16x16x32_f16(ah, bh[b], aM[a][b], 0, 0, 0);
                    aX[a][b] = __builtin_amdgcn_mfma_f32_16x16x32_f16(ah, bl[b], aX[a][b], 0, 0, 0);
                    aX[a][b] = __builtin_amdgcn_mfma_f32_16x16x32_f16(al, bh[b], aX[a][b], 0, 0, 0);
                }
            }
        }
    }

#pragma unroll
    for (int a = 0; a < 2; ++a) {
        int oy = oy0 + wm * 2 + a;
#pragma unroll
        for (int b = 0; b < 2; ++b) {
            int co = co0 + (wn * 2 + b) * 16 + (l & 15);
            float bj = (KSPLIT == 1) ? bias[co] : 0.0f;
#pragma unroll
            for (int r = 0; r < 4; ++r) {
                int ox = ox0 + (l >> 4) * 4 + r;
                float v = aM[a][b][r] + aX[a][b][r] * (1.0f / 4096.0f) + bj;
                size_t oidx = ((size_t)(n * Ho + oy) * Wo + ox) * Co + co;
                if (KSPLIT > 1) {
                    ((float*)outp)[(size_t)ks * (16 * Ho * Wo * Co) + oidx] = v;
                } else {
                    if (GELU) v = gelu_tanh(v);
                    if (SPLIT) ((u32*)outp)[oidx] = pack_split(v);
                    else       ((float*)outp)[oidx] = v;
                }
            }
        }
    }
}

// ---- reduce conv4 partials + bias -> NHWC fp32 latent --------------------
__global__ void reduce4_k(const float* __restrict__ part,
                          const float* __restrict__ bias,
                          float* __restrict__ out) {
    constexpr int PS4 = 16 * 16 * 16 * 256 / 4;   // partial stride in float4
    int gid = blockIdx.x * 256 + threadIdx.x;     // 262144 total
    const float4* p = (const float4*)part;
    float4 s = p[gid];
    float4 q1 = p[PS4 + gid];
    float4 q2 = p[2 * PS4 + gid];
    float4 q3 = p[3 * PS4 + gid];
    s.x += q1.x; s.y += q1.y; s.z += q1.z; s.w += q1.w;
    s.x += q2.x; s.y += q2.y; s.z += q2.z; s.w += q2.w;
    s.x += q3.x; s.y += q3.y; s.z += q3.z; s.w += q3.w;
    float4 b = *(const float4*)&bias[(gid * 4) & 255];
    s.x += b.x; s.y += b.y; s.z += b.z; s.w += b.w;
    ((float4*)out)[gid] = s;
}

// ---- head precompute ------------------------------------------------------
__global__ void kproj_kernel(const float* __restrict__ cb,
                             const float* __restrict__ wk,
                             float* __restrict__ kp) {
    int m = blockIdx.x >> 8;
    int k = blockIdx.x & 255;
    int c = threadIdx.x;
    const float* cbp = cb + (size_t)(m * 256 + k) * 64;
    const float* wkp = wk + (size_t)(m * 64 + c) * 64;
    float acc = 0.0f;
#pragma unroll 8
    for (int d = 0; d < 64; ++d) acc += cbp[d] * wkp[d];
    kp[(size_t)(m * 256 + k) * 64 + c] = acc;
}

__global__ void m_kernel(const float* __restrict__ wq,
                         const float* __restrict__ kp,
                         float* __restrict__ M) {
    int m = blockIdx.x >> 8;
    int k = blockIdx.x & 255;
    int d = threadIdx.x;
    const float* kpp = &kp[(size_t)(m * 256 + k) * 64];
    const float* wqp = &wq[(size_t)m * 64 * 64 + d];
    float acc = 0.0f;
#pragma unroll 8
    for (int c = 0; c < 64; ++c) acc += wqp[c * 64] * kpp[c];
    M[((size_t)(m * 256 + k)) * 64 + d] = acc;
}

// ---- head: scores = lat . M, argmax over k -------------------------------
// block = 4px x 4m x 16kq; thread scans 16 codes; grid 1024 (4 blocks/CU).
__launch_bounds__(256)
__global__ void head_kernel(const float* __restrict__ latent,  // NHWC fp32
                            const float* __restrict__ M,
                            int* __restrict__ out) {
    __shared__ float rs[256];
    __shared__ int rk[256];
    const int t = threadIdx.x;
    const int px = t & 3, m = (t >> 2) & 3, kq = t >> 4;   // kq 0..15
    const int pix = blockIdx.x * 4 + px;

    float4 lr[16];
    const float4* lp = (const float4*)&latent[(size_t)pix * 256 + m * 64];
#pragma unroll
    for (int d = 0; d < 16; ++d) lr[d] = lp[d];

    float best = -INFINITY;
    int bestk = 0;
    const float4* Mp = (const float4*)&M[(size_t)(m * 256 + kq * 16) * 64];
#pragma unroll 4
    for (int kk = 0; kk < 16; ++kk) {
        float s0 = 0.0f, s1 = 0.0f, s2 = 0.0f, s3 = 0.0f;
#pragma unroll
        for (int d = 0; d < 16; ++d) {
            float4 mv = Mp[kk * 16 + d];
            s0 += lr[d].x * mv.x; s1 += lr[d].y * mv.y;
            s2 += lr[d].z * mv.z; s3 += lr[d].w * mv.w;
        }
        float s = (s0 + s1) + (s2 + s3);
        if (s > best) { best = s; bestk = kq * 16 + kk; }  // ascending: keeps lowest
    }
    rs[t] = best; rk[t] = bestk;
    __syncthreads();
    if (kq == 0) {
#pragma unroll
        for (int q = 1; q < 16; ++q) {                     // ascending kq ranges
            float sv = rs[t + 16 * q];
            int kv = rk[t + 16 * q];
            if (sv > best || (sv == best && kv < bestk)) { best = sv; bestk = kv; }
        }
        out[pix * 4 + m] = bestk;
    }
    if (blockIdx.x == 0 && t == 0) { out[16384] = 256; out[16385] = 256; }
}

extern "C" void kernel_launch(void* const* d_in, const int* in_sizes, int n_in,
                              void* d_out, int out_size, void* d_ws, size_t ws_size,
                              hipStream_t stream) {
    const float* x  = (const float*)d_in[0];
    const float* w1 = (const float*)d_in[1];  const float* b1 = (const float*)d_in[2];
    const float* w2 = (const float*)d_in[3];  const float* b2 = (const float*)d_in[4];
    const float* w3 = (const float*)d_in[5];  const float* b3 = (const float*)d_in[6];
    const float* w4 = (const float*)d_in[7];  const float* b4 = (const float*)d_in[8];
    const float* cb = (const float*)d_in[9];
    const float* wq = (const float*)d_in[10];
    const float* wk = (const float*)d_in[11];
    int* out = (int*)d_out;

    char* ws = (char*)d_ws;
    u32*   buf1 = (u32*)ws;                         // 16*128*128*64 u32 = 64 MiB
    u32*   buf2 = (u32*)(ws + 67108864);            // 16*64*64*128  u32 = 32 MiB
    u32*   buf3 = (u32*)(ws + 100663296);           // 16*32*32*256  u32 = 16 MiB
    float* buf4 = (float*)(ws + 117440512);         // 16*16*16*256  f32 =  4 MiB
    float* kp   = (float*)(ws + 121634816);         // 256 KiB
    float* Mbuf = (float*)(ws + 121634816 + 262144);// 256 KiB

    _Float16* w2H = (_Float16*)(ws + 100663296);    // in buf3 (dead until conv3)
    _Float16* w2L = w2H + 9 * 2 * 8 * 512;
    _Float16* w3H = (_Float16*)ws;                  // in buf1 (dead after conv2)
    _Float16* w3L = w3H + 9 * 4 * 16 * 512;
    _Float16* w4H = w3L + 9 * 4 * 16 * 512;
    _Float16* w4L = w4H + 9 * 8 * 16 * 512;
    float* part4 = (float*)(ws + 67108864);         // buf2 region (dead after conv3), 16 MiB

    prep_w<64, 128><<<36, 256, 0, stream>>>(w2, w2H, w2L);
    conv1_k<<<1024, 256, 0, stream>>>(x, w1, b1, buf1);
    conv_mfma<64, 128, 128, 128, 8, 1, true, true><<<1024, 512, 0, stream>>>(buf1, w2H, w2L, b2, buf2);
    prep_w<128, 256><<<144, 256, 0, stream>>>(w3, w3H, w3L);
    prep_w<256, 256><<<288, 256, 0, stream>>>(w4, w4H, w4L);
    conv_mfma<128, 256, 64, 64, 8, 1, true, true><<<512, 512, 0, stream>>>(buf2, w3H, w3L, b3, buf3);
    kproj_kernel<<<4 * 256, 64, 0, stream>>>(cb, wk, kp);
    m_kernel<<<4 * 256, 64, 0, stream>>>(wq, kp, Mbuf);
    conv_mfma<256, 256, 32, 32, 4, 4, false, false><<<1024, 256, 0, stream>>>(buf3, w4H, w4L, b4, part4);
    reduce4_k<<<1024, 256, 0, stream>>>(part4, b4, buf4);
    head_kernel<<<1024, 256, 0, stream>>>(buf4, Mbuf, out);
}

// Round 20
// 275.289 us; speedup vs baseline: 1.1118x; 1.0655x over previous
//
#include <hip/hip_runtime.h>
#include <math.h>

// ---------------------------------------------------------------------------
// RefEncoder, MFMA edition (round 20: round-17 best + launch fusions — kproj+m
// merged via LDS, prep_w3/w4 merged into one launch; 11 -> 9 kernels).
// gelu via v_exp_f32 sigmoid form.
// conv1: fp32 direct, float4-staged 17x260 window, weights LDS broadcast.
// conv2/3/4: implicit-GEMM via v_mfma_f32_16x16x32_f16, fp16 2-term split:
//   x = hi + lo/4096;  C = A_hi*B_hi ; Ccross = A_hi*B_lo' + A_lo'*B_hi
//   result = C + Ccross/4096 (dropped al*bl ~2^-24 rel: fp32-class)
// B fragments per-wave from global (fragment-ordered, L2-resident), no B-LDS.
// conv4: NWAVE=4 + KSPLIT=4, fp32 partials; reduce4_k + bias.
// head: block = 4px x 4m x 16kq, 16 codes/thread, grid 1024.
// Output (int32): 16384 codes [n,hh,ww,m] + tail [256,256]
// ---------------------------------------------------------------------------

typedef _Float16 half8 __attribute__((ext_vector_type(8)));
typedef float floatx4 __attribute__((ext_vector_type(4)));
typedef unsigned int u32;
typedef unsigned short u16;

__device__ __forceinline__ float gelu_tanh(float x) {
    // x * sigmoid(1.5957691216*x + 0.07135481627*x^3)  (== tanh-form gelu)
    float x3 = x * x * x;
    float t = 1.5957691216057308f * x + 0.07135481627333636f * x3;
    return x / (1.0f + __expf(-t));
}

__device__ __forceinline__ u32 pack_split(float v) {
    _Float16 h = (_Float16)v;
    _Float16 l = (_Float16)((v - (float)h) * 4096.0f);
    union { _Float16 f; u16 s; } a, b;
    a.f = h; b.f = l;
    return (u32)a.s | ((u32)b.s << 16);
}

// ---- weight prep: OIHW fp32 -> B-fragment-ordered fp16 hi/lo planes -------
template <int Ci, int Co>
__device__ __forceinline__ void prep_body(const float* __restrict__ W,
                                          _Float16* __restrict__ dH,
                                          _Float16* __restrict__ dL, int lin) {
    constexpr int KC = Ci / 32, NTg = Co / 16;
    if (lin >= 9 * KC * NTg * 64) return;
    int l = lin & 63;
    int q = lin >> 6;
    int nt = q % NTg; q /= NTg;
    int kc = q % KC;
    int tap = q / KC;
    int co = nt * 16 + (l & 15);
    int ci0 = kc * 32 + ((l >> 4) << 3);
#pragma unroll
    for (int j = 0; j < 8; ++j) {
        float v = W[((size_t)co * Ci + ci0 + j) * 9 + tap];
        _Float16 h = (_Float16)v;
        _Float16 lo = (_Float16)((v - (float)h) * 4096.0f);
        dH[(size_t)lin * 8 + j] = h;
        dL[(size_t)lin * 8 + j] = lo;
    }
}

template <int Ci, int Co>
__global__ void prep_w(const float* __restrict__ W, _Float16* __restrict__ dH,
                       _Float16* __restrict__ dL) {
    prep_body<Ci, Co>(W, dH, dL, blockIdx.x * 256 + threadIdx.x);
}

// fused prep for conv3 + conv4 weights (one launch, branch by block range)
__global__ void prep_w34(const float* __restrict__ W3, _Float16* __restrict__ d3H,
                         _Float16* __restrict__ d3L, const float* __restrict__ W4,
                         _Float16* __restrict__ d4H, _Float16* __restrict__ d4L) {
    int b = blockIdx.x;
    if (b < 144) prep_body<128, 256>(W3, d3H, d3L, b * 256 + threadIdx.x);
    else         prep_body<256, 256>(W4, d4H, d4L, (b - 144) * 256 + threadIdx.x);
}

// ---- conv1: 3->64, fp32 direct (round-12 tile), float4 staging -----------
__launch_bounds__(256)
__global__ void conv1_k(const float* __restrict__ x, const float* __restrict__ w,
                        const float* __restrict__ bias, u32* __restrict__ out) {
    __shared__ float win[17 * 260];     // one ci slice, rows iy0..iy0+16
    __shared__ float wsh[27 * 64];      // [ci*9+tap][co]
    const int t = threadIdx.x;
    const int tx = t & 15, ty = (t >> 4) & 7, cz = t >> 7;
    int bx = blockIdx.x;
    const int cg = bx & 3;
    const int oyt = (bx >> 2) & 15;
    const int n = bx >> 6;
    const int co0 = cg * 16 + cz * 8;
    const int oy = oyt * 8 + ty;
    const int ox0 = tx * 8;
    const int iy0 = oyt * 16;

    for (int e = t; e < 27 * 64; e += 256) {
        int co = e & 63, ct = e >> 6;   // ct = ci*9+ky*3+kx
        wsh[ct * 64 + co] = w[co * 27 + ct];
    }

    float acc[8][8];
#pragma unroll
    for (int c = 0; c < 8; ++c)
#pragma unroll
        for (int p = 0; p < 8; ++p) acc[c][p] = 0.0f;

    for (int ci = 0; ci < 3; ++ci) {
        __syncthreads();
        // float4 staging: 17 rows x 65 quads (quad 64 = cols 256..259 = pad)
        for (int e = t; e < 17 * 65; e += 256) {
            int r = e / 65, c4 = (e - r * 65) * 4;
            int iy = iy0 + r;
            float4 v = {0.0f, 0.0f, 0.0f, 0.0f};
            if (c4 < 256 && iy < 256) {
                float4 g = *(const float4*)&x[((size_t)(n * 3 + ci) * 256 + iy) * 256 + c4];
                v.x = 2.0f * g.x - 1.0f; v.y = 2.0f * g.y - 1.0f;
                v.z = 2.0f * g.z - 1.0f; v.w = 2.0f * g.w - 1.0f;
            }
            *(float4*)&win[r * 260 + c4] = v;
        }
        __syncthreads();

#pragma unroll
        for (int ky = 0; ky < 3; ++ky) {
            const float* rowp = &win[(2 * ty + ky) * 260 + 16 * tx];
            float rv[20];
#pragma unroll
            for (int q = 0; q < 5; ++q) {
                float4 v4 = *(const float4*)(rowp + 4 * q);
                rv[4 * q + 0] = v4.x; rv[4 * q + 1] = v4.y;
                rv[4 * q + 2] = v4.z; rv[4 * q + 3] = v4.w;
            }
#pragma unroll
            for (int kx = 0; kx < 3; ++kx) {
                const float* wp = &wsh[(ci * 9 + ky * 3 + kx) * 64 + co0];
                float wv[8];
#pragma unroll
                for (int q = 0; q < 2; ++q) {
                    float4 v4 = *(const float4*)(wp + 4 * q);  // broadcast
                    wv[4 * q + 0] = v4.x; wv[4 * q + 1] = v4.y;
                    wv[4 * q + 2] = v4.z; wv[4 * q + 3] = v4.w;
                }
#pragma unroll
                for (int c = 0; c < 8; ++c)
#pragma unroll
                    for (int p = 0; p < 8; ++p)
                        acc[c][p] += rv[2 * p + kx] * wv[c];
            }
        }
    }

    float bj[8];
#pragma unroll
    for (int c = 0; c < 8; ++c) bj[c] = bias[co0 + c];
#pragma unroll
    for (int p = 0; p < 8; ++p) {
        int ox = ox0 + p;
        size_t base = ((size_t)(n * 128 + oy) * 128 + ox) * 64 + co0;
        uint4 s0, s1;
        s0.x = pack_split(gelu_tanh(acc[0][p] + bj[0]));
        s0.y = pack_split(gelu_tanh(acc[1][p] + bj[1]));
        s0.z = pack_split(gelu_tanh(acc[2][p] + bj[2]));
        s0.w = pack_split(gelu_tanh(acc[3][p] + bj[3]));
        s1.x = pack_split(gelu_tanh(acc[4][p] + bj[4]));
        s1.y = pack_split(gelu_tanh(acc[5][p] + bj[5]));
        s1.z = pack_split(gelu_tanh(acc[6][p] + bj[6]));
        s1.w = pack_split(gelu_tanh(acc[7][p] + bj[7]));
        *(uint4*)&out[base] = s0;
        *(uint4*)&out[base + 4] = s1;
    }
}

// ---- MFMA conv: stride-2 3x3, NHWC packed-half2 in (round-17 body) -------
template <int Ci, int Co, int Hi, int Wi, int NWAVE, int KSPLIT, bool GELU, bool SPLIT>
__launch_bounds__(NWAVE * 64)
__global__ void conv_mfma(const u32* __restrict__ in, const _Float16* __restrict__ WbH,
                          const _Float16* __restrict__ WbL, const float* __restrict__ bias,
                          void* __restrict__ outp) {
    constexpr int Ho = Hi / 2, Wo = Wi / 2;
    constexpr int KC = Ci / 32, NTg = Co / 16;
    constexpr int OYT = Ho / 4, OXT = Wo / 16, CGT = Co / (16 * NWAVE);
    constexpr int WC = 33, CIBP = 40;
    constexpr int NT = NWAVE * 64;
    constexpr int KCS = KC / KSPLIT;
    __shared__ _Float16 AH[9 * WC * CIBP], AL[9 * WC * CIBP];  // 47.5 KB total

    const int t = threadIdx.x, l = t & 63, wid = t >> 6;
    const int wm = wid / (NWAVE / 2), wn = wid % (NWAVE / 2);
    int bx = blockIdx.x;
    const int ks = bx % KSPLIT;  bx /= KSPLIT;
    const int cg = bx % CGT;  bx /= CGT;
    const int oxt = bx % OXT; bx /= OXT;
    const int oyt = bx % OYT; bx /= OYT;
    const int n = bx;
    const int oy0 = oyt * 4, ox0 = oxt * 16, co0 = cg * 16 * NWAVE, nt0 = co0 >> 4;
    const int iy0 = oy0 * 2, ix0 = ox0 * 2;

    floatx4 aM[2][2], aX[2][2];
    floatx4 zz = {0.0f, 0.0f, 0.0f, 0.0f};
#pragma unroll
    for (int a = 0; a < 2; ++a)
#pragma unroll
        for (int b = 0; b < 2; ++b) { aM[a][b] = zz; aX[a][b] = zz; }

    const int bfrag = (wn * 2) * 512 + l * 8;

    for (int kc = ks * KCS; kc < (ks + 1) * KCS; ++kc) {
        __syncthreads();
        for (int e = t; e < 9 * WC * 4; e += NT) {
            int og = e & 3, px = e >> 2;
            int r = px / WC, cx = px - r * WC;
            int iy = iy0 + r, ix = ix0 + cx;
            union { float4 f4[2]; u32 u[8]; } buf;
            if (iy < Hi && ix < Wi) {
                const float4* g = (const float4*)(in + (((size_t)(n * Hi + iy) * Wi + ix) * Ci + kc * 32 + og * 8));
                buf.f4[0] = g[0]; buf.f4[1] = g[1];
            } else {
#pragma unroll
                for (int k2 = 0; k2 < 8; ++k2) buf.u[k2] = 0;
            }
            union { float4 f4; u16 s[8]; } hh, ll;
#pragma unroll
            for (int k2 = 0; k2 < 8; ++k2) {
                hh.s[k2] = (u16)buf.u[k2];
                ll.s[k2] = (u16)(buf.u[k2] >> 16);
            }
            int off = px * CIBP + og * 8;
            *(float4*)&AH[off] = hh.f4;
            *(float4*)&AL[off] = ll.f4;
        }
        __syncthreads();

#pragma unroll
        for (int tap = 0; tap < 9; ++tap) {
            const size_t src = ((size_t)(tap * KC + kc) * NTg + nt0) * 512 + bfrag;
            half8 bh[2], bl[2];
#pragma unroll
            for (int b = 0; b < 2; ++b) {
                bh[b] = *(const half8*)&WbH[src + b * 512];
                bl[b] = *(const half8*)&WbL[src + b * 512];
            }
            const int ky = tap / 3, kx = tap - ky * 3;
#pragma unroll
            for (int a = 0; a < 2; ++a) {
                int mt = wm * 2 + a;
                int off = ((2 * mt + ky) * WC + 2 * (l & 15) + kx) * CIBP + (l >> 4) * 8;
                half8 ah = *(half8*)&AH[off];
                half8 al = *(half8*)&AL[off];
#pragma unroll
                for (int b = 0; b < 2; ++b) {
                    aM[a][b] = __builtin_amdgcn_mfma_f32_16x16x32_f16(ah, bh[b], aM[a][b], 0, 0, 0);
                    aX[a][b] = __builtin_amdgcn_mfma_f32_16x16x32_f16(ah, bl[b], aX[a][b], 0, 0, 0);
                    aX[a][b] = __builtin_amdgcn_mfma_f32_16x16x32_f16(al, bh[b], aX[a][b], 0, 0, 0);
                }
            }
        }
    }

#pragma unroll
    for (int a = 0; a < 2; ++a) {
        int oy = oy0 + wm * 2 + a;
#pragma unroll
        for (int b = 0; b < 2; ++b) {
            int co = co0 + (wn * 2 + b) * 16 + (l & 15);
            float bj = (KSPLIT == 1) ? bias[co] : 0.0f;
#pragma unroll
            for (int r = 0; r < 4; ++r) {
                int ox = ox0 + (l >> 4) * 4 + r;
                float v = aM[a][b][r] + aX[a][b][r] * (1.0f / 4096.0f) + bj;
                size_t oidx = ((size_t)(n * Ho + oy) * Wo + ox) * Co + co;
                if (KSPLIT > 1) {
                    ((float*)outp)[(size_t)ks * (16 * Ho * Wo * Co) + oidx] = v;
                } else {
                    if (GELU) v = gelu_tanh(v);
                    if (SPLIT) ((u32*)outp)[oidx] = pack_split(v);
                    else       ((float*)outp)[oidx] = v;
                }
            }
        }
    }
}

// ---- reduce conv4 partials + bias -> NHWC fp32 latent --------------------
__global__ void reduce4_k(const float* __restrict__ part,
                          const float* __restrict__ bias,
                          float* __restrict__ out) {
    constexpr int PS4 = 16 * 16 * 16 * 256 / 4;   // partial stride in float4
    int gid = blockIdx.x * 256 + threadIdx.x;     // 262144 total
    const float4* p = (const float4*)part;
    float4 s = p[gid];
    float4 q1 = p[PS4 + gid];
    float4 q2 = p[2 * PS4 + gid];
    float4 q3 = p[3 * PS4 + gid];
    s.x += q1.x; s.y += q1.y; s.z += q1.z; s.w += q1.w;
    s.x += q2.x; s.y += q2.y; s.z += q2.z; s.w += q2.w;
    s.x += q3.x; s.y += q3.y; s.z += q3.z; s.w += q3.w;
    float4 b = *(const float4*)&bias[(gid * 4) & 255];
    s.x += b.x; s.y += b.y; s.z += b.z; s.w += b.w;
    ((float4*)out)[gid] = s;
}

// ---- fused head precompute: kproj row in LDS -> M row --------------------
// M[m][k][d] = sum_c wq[m][c][d] * (sum_dd cb[m][k][dd] * wk[m][c][dd])
__global__ void kprojm_k(const float* __restrict__ cb,
                         const float* __restrict__ wk,
                         const float* __restrict__ wq,
                         float* __restrict__ M) {
    __shared__ float kp[64];
    int m = blockIdx.x >> 8;
    int k = blockIdx.x & 255;
    int c = threadIdx.x;
    const float* cbp = cb + (size_t)(m * 256 + k) * 64;
    const float* wkp = wk + (size_t)(m * 64 + c) * 64;
    float acc = 0.0f;
#pragma unroll 8
    for (int d = 0; d < 64; ++d) acc += cbp[d] * wkp[d];
    kp[c] = acc;
    __syncthreads();
    int d = threadIdx.x;
    const float* wqp = &wq[(size_t)m * 64 * 64 + d];   // wq[m][c][d], stride 64
    float a2 = 0.0f;
#pragma unroll 8
    for (int c2 = 0; c2 < 64; ++c2) a2 += wqp[c2 * 64] * kp[c2];
    M[((size_t)(m * 256 + k)) * 64 + d] = a2;
}

// ---- head: scores = lat . M, argmax over k -------------------------------
// block = 4px x 4m x 16kq; thread scans 16 codes; grid 1024 (4 blocks/CU).
__launch_bounds__(256)
__global__ void head_kernel(const float* __restrict__ latent,  // NHWC fp32
                            const float* __restrict__ M,
                            int* __restrict__ out) {
    __shared__ float rs[256];
    __shared__ int rk[256];
    const int t = threadIdx.x;
    const int px = t & 3, m = (t >> 2) & 3, kq = t >> 4;   // kq 0..15
    const int pix = blockIdx.x * 4 + px;

    float4 lr[16];
    const float4* lp = (const float4*)&latent[(size_t)pix * 256 + m * 64];
#pragma unroll
    for (int d = 0; d < 16; ++d) lr[d] = lp[d];

    float best = -INFINITY;
    int bestk = 0;
    const float4* Mp = (const float4*)&M[(size_t)(m * 256 + kq * 16) * 64];
#pragma unroll 4
    for (int kk = 0; kk < 16; ++kk) {
        float s0 = 0.0f, s1 = 0.0f, s2 = 0.0f, s3 = 0.0f;
#pragma unroll
        for (int d = 0; d < 16; ++d) {
            float4 mv = Mp[kk * 16 + d];
            s0 += lr[d].x * mv.x; s1 += lr[d].y * mv.y;
            s2 += lr[d].z * mv.z; s3 += lr[d].w * mv.w;
        }
        float s = (s0 + s1) + (s2 + s3);
        if (s > best) { best = s; bestk = kq * 16 + kk; }  // ascending: keeps lowest
    }
    rs[t] = best; rk[t] = bestk;
    __syncthreads();
    if (kq == 0) {
#pragma unroll
        for (int q = 1; q < 16; ++q) {                     // ascending kq ranges
            float sv = rs[t + 16 * q];
            int kv = rk[t + 16 * q];
            if (sv > best || (sv == best && kv < bestk)) { best = sv; bestk = kv; }
        }
        out[pix * 4 + m] = bestk;
    }
    if (blockIdx.x == 0 && t == 0) { out[16384] = 256; out[16385] = 256; }
}

extern "C" void kernel_launch(void* const* d_in, const int* in_sizes, int n_in,
                              void* d_out, int out_size, void* d_ws, size_t ws_size,
                              hipStream_t stream) {
    const float* x  = (const float*)d_in[0];
    const float* w1 = (const float*)d_in[1];  const float* b1 = (const float*)d_in[2];
    const float* w2 = (const float*)d_in[3];  const float* b2 = (const float*)d_in[4];
    const float* w3 = (const float*)d_in[5];  const float* b3 = (const float*)d_in[6];
    const float* w4 = (const float*)d_in[7];  const float* b4 = (const float*)d_in[8];
    const float* cb = (const float*)d_in[9];
    const float* wq = (const float*)d_in[10];
    const float* wk = (const float*)d_in[11];
    int* out = (int*)d_out;

    char* ws = (char*)d_ws;
    u32*   buf1 = (u32*)ws;                         // 16*128*128*64 u32 = 64 MiB
    u32*   buf2 = (u32*)(ws + 67108864);            // 16*64*64*128  u32 = 32 MiB
    u32*   buf3 = (u32*)(ws + 100663296);           // 16*32*32*256  u32 = 16 MiB
    float* buf4 = (float*)(ws + 117440512);         // 16*16*16*256  f32 =  4 MiB
    float* Mbuf = (float*)(ws + 121634816);         // 256 KiB

    _Float16* w2H = (_Float16*)(ws + 100663296);    // in buf3 (dead until conv3)
    _Float16* w2L = w2H + 9 * 2 * 8 * 512;
    _Float16* w3H = (_Float16*)ws;                  // in buf1 (dead after conv2)
    _Float16* w3L = w3H + 9 * 4 * 16 * 512;
    _Float16* w4H = w3L + 9 * 4 * 16 * 512;
    _Float16* w4L = w4H + 9 * 8 * 16 * 512;
    float* part4 = (float*)(ws + 67108864);         // buf2 region (dead after conv3), 16 MiB

    prep_w<64, 128><<<36, 256, 0, stream>>>(w2, w2H, w2L);
    conv1_k<<<1024, 256, 0, stream>>>(x, w1, b1, buf1);
    conv_mfma<64, 128, 128, 128, 8, 1, true, true><<<1024, 512, 0, stream>>>(buf1, w2H, w2L, b2, buf2);
    prep_w34<<<144 + 288, 256, 0, stream>>>(w3, w3H, w3L, w4, w4H, w4L);
    conv_mfma<128, 256, 64, 64, 8, 1, true, true><<<512, 512, 0, stream>>>(buf2, w3H, w3L, b3, buf3);
    kprojm_k<<<4 * 256, 64, 0, stream>>>(cb, wk, wq, Mbuf);
    conv_mfma<256, 256, 32, 32, 4, 4, false, false><<<1024, 256, 0, stream>>>(buf3, w4H, w4L, b4, part4);
    reduce4_k<<<1024, 256, 0, stream>>>(part4, b4, buf4);
    head_kernel<<<1024, 256, 0, stream>>>(buf4, Mbuf, out);
}